// Round 3
// baseline (2001.031 us; speedup 1.0000x reference)
//
#include <hip/hip_runtime.h>
#include <hip/hip_bf16.h>
#include <math.h>

#define H 128
#define TILE 64
#define XB_STRIDE 136   // shorts per xb row (272B) -> 2-way bank aliasing (free)
#define WB_STRIDE 9     // floats per wbuf row (36B) -> 2-way on scalar reads
#define MB_STRIDE 136   // merge buffer row-block stride

typedef __attribute__((ext_vector_type(8))) short bf16x8;
typedef __attribute__((ext_vector_type(4))) float f32x4;

__device__ __forceinline__ short f2bf(float f) {
  union { float f; unsigned u; } v; v.f = f;
  unsigned r = v.u + 0x7fffu + ((v.u >> 16) & 1u);  // round-to-nearest-even
  return (short)(r >> 16);
}

// ---- K0: W1 (fp32, [k][n]) -> W1T bf16 [n][k], so B-frags are contiguous 16B ----
__global__ void prep_kernel(const float* __restrict__ w1, short* __restrict__ w1t) {
  int i = blockIdx.x * blockDim.x + threadIdx.x;   // 0 .. H*H-1
  if (i >= H * H) return;
  int k = i >> 7, n = i & (H - 1);
  w1t[n * H + k] = f2bf(w1[k * H + n]);
}

// ---- K1: segment boundaries from sorted batch_index ----
__global__ void bounds_kernel(const int* __restrict__ bi, int* __restrict__ seg_start,
                              int N, int B) {
  int n = blockIdx.x * blockDim.x + threadIdx.x;
  if (n >= N) return;
  int cur = bi[n];
  int prev = (n == 0) ? -1 : bi[n - 1];
  for (int g = prev + 1; g <= cur; ++g) seg_start[g] = n;
  if (n == N - 1) {
    for (int g = cur + 1; g <= B; ++g) seg_start[g] = N;
  }
}

// ---- K2: fused per-graph readout. 8 waves x 16 cols; 2 barriers/tile;
//      all-wave duplicated softmax reduce; weights broadcast via shfl. ----
__global__ __launch_bounds__(512, 7) void fused_kernel(
    const float* __restrict__ x, const short* __restrict__ w1t,
    const float* __restrict__ b1, const float* __restrict__ w2,
    const float* __restrict__ b2, const int* __restrict__ seg_start,
    float* __restrict__ out)
{
  // overlay: {xb 17408B, wbuf 2304B} reused as mb[3][16][136] (26112B) after loop
  __shared__ __align__(16) char smem[3 * 16 * MB_STRIDE * 4];
  short* xb   = (short*)smem;
  float* wbuf = (float*)(smem + TILE * XB_STRIDE * 2);
  float* mb   = (float*)smem;

  const int g = blockIdx.x;
  const int s = seg_start[g];
  const int R = seg_start[g + 1] - s;

  const int tid  = threadIdx.x;
  const int w    = tid >> 6;       // wave 0..7 -> cols [16w, 16w+16)
  const int lane = tid & 63;
  const int l15  = lane & 15;
  const int q    = lane >> 4;

  // staging/pool identity: cols [c4, c4+4), rows rb + 16i (i=0..3)
  const int c4 = (tid & 31) * 4;
  const int rb = tid >> 5;         // 0..15

  float4 sum4 = make_float4(0.f, 0.f, 0.f, 0.f);
  float4 mx4  = make_float4(-INFINITY, -INFINITY, -INFINITY, -INFINITY);
  float4 av4  = make_float4(0.f, 0.f, 0.f, 0.f);
  float m_run = -INFINITY, l_run = 0.f;

  const float b2v  = b2[0];
  const int   c0   = 16 * w + l15;   // this thread's output column
  const float w2c0 = w2[c0];
  const float b1c0 = b1[c0];

  const float* xp = x + (size_t)s * H + c4;

  for (int t0 = 0; t0 < R; t0 += TILE) {
    const int Rt    = min(TILE, R - t0);
    const int mtMax = (Rt + 15) >> 4;          // skip all-OOB M-subtiles
    const float* xt = xp + (size_t)t0 * H;

    // ---- stage: global fp32 -> LDS bf16; fold sum/max; no register retention ----
#pragma unroll
    for (int i = 0; i < 4; ++i) {
      const int row = rb + 16 * i;
      float4 v = make_float4(0.f, 0.f, 0.f, 0.f);
      if (row < Rt) {
        v = *(const float4*)(xt + (size_t)row * H);
        sum4.x += v.x; sum4.y += v.y; sum4.z += v.z; sum4.w += v.w;
        mx4.x = fmaxf(mx4.x, v.x); mx4.y = fmaxf(mx4.y, v.y);
        mx4.z = fmaxf(mx4.z, v.z); mx4.w = fmaxf(mx4.w, v.w);
      }
      short4 sv = make_short4(f2bf(v.x), f2bf(v.y), f2bf(v.z), f2bf(v.w));
      *(short4*)(&xb[row * XB_STRIDE + c4]) = sv;   // zeros for OOB rows
    }
    __syncthreads();   // sync1: xb ready (also fences prev-tile wbuf readers)

    // ---- gate GEMM: 64 rows x 16 cols per wave ----
    f32x4 acc[4] = {};
#pragma unroll
    for (int kc = 0; kc < H; kc += 32) {
      const bf16x8 b = *(const bf16x8*)(w1t + c0 * H + kc + 8 * q);
#pragma unroll
      for (int mt = 0; mt < 4; ++mt) {
        if (mt < mtMax) {
          const bf16x8 a = *(const bf16x8*)(&xb[(16 * mt + l15) * XB_STRIDE + kc + 8 * q]);
          acc[mt] = __builtin_amdgcn_mfma_f32_16x16x32_bf16(a, b, acc[mt], 0, 0, 0);
        }
      }
    }

    // ---- epilogue: silu(h)*w2, 16-lane shfl reduce -> wbuf[row][w] ----
#pragma unroll
    for (int mt = 0; mt < 4; ++mt) {
      if (mt < mtMax) {
#pragma unroll
        for (int r = 0; r < 4; ++r) {
          float h0 = acc[mt][r] + b1c0;
          float s0 = h0 / (1.0f + __expf(-h0));
          float p  = s0 * w2c0;
          p += __shfl_xor(p, 1);
          p += __shfl_xor(p, 2);
          p += __shfl_xor(p, 4);
          p += __shfl_xor(p, 8);
          if (l15 == 0) wbuf[(16 * mt + 4 * q + r) * WB_STRIDE + w] = p;
        }
      }
    }
    __syncthreads();   // sync2: wbuf ready (also fences xb readers before next stage)

    // ---- all waves duplicate: per-row gate, tile max/denom, in-register weights ----
    {
      const int row = lane;
      float gate = b2v;
#pragma unroll
      for (int j = 0; j < 8; ++j) gate += wbuf[row * WB_STRIDE + j];
      const bool valid = row < Rt;
      float gm = valid ? gate : -INFINITY;
#pragma unroll
      for (int m2 = 1; m2 < 64; m2 <<= 1) gm = fmaxf(gm, __shfl_xor(gm, m2));
      const float m_new = fmaxf(m_run, gm);
      const float wv = valid ? __expf(gate - m_new) : 0.f;
      float tl = wv;
#pragma unroll
      for (int m2 = 1; m2 < 64; m2 <<= 1) tl += __shfl_xor(tl, m2);
      const float corr = __expf(m_run - m_new);   // first tile: exp(-inf)=0
      m_run = m_new;
      l_run = l_run * corr + tl;
      av4.x *= corr; av4.y *= corr; av4.z *= corr; av4.w *= corr;

      // ---- pool: re-read x (L2-hot), weights via in-wave shfl, 1 fma/elem ----
#pragma unroll
      for (int i = 0; i < 4; ++i) {
        const int row2 = rb + 16 * i;
        const float wvi = __shfl(wv, row2);      // wv==0 for rows >= Rt
        if (row2 < Rt) {
          const float4 v = *(const float4*)(xt + (size_t)row2 * H);
          av4.x += wvi * v.x; av4.y += wvi * v.y;
          av4.z += wvi * v.z; av4.w += wvi * v.w;
        }
      }
    }
    // no barrier: next stage writes xb only after passing sync2-protected path;
    // next wbuf write is after sync1(t+1), which requires all waves done here.
  }

  __syncthreads();   // all waves done with xb/wbuf before overlaying mb

  // ---- merge the 16 row-block partials per column (mb overlays smem) ----
  {
    const int base = rb * MB_STRIDE + c4;
    *(float4*)(&mb[       base]) = sum4;
    *(float4*)(&mb[2176 + base]) = mx4;
    *(float4*)(&mb[4352 + base]) = av4;
  }
  __syncthreads();
  if (tid < H) {
    const int c = tid;
    float sv = 0.f, mv = -INFINITY, av = 0.f;
#pragma unroll
    for (int r16 = 0; r16 < 16; ++r16) {
      sv += mb[r16 * MB_STRIDE + c];
      mv  = fmaxf(mv, mb[2176 + r16 * MB_STRIDE + c]);
      av += mb[4352 + r16 * MB_STRIDE + c];
    }
    float* og = out + (size_t)g * (3 * H);
    og[c]         = sv / fmaxf((float)R, 1.0f);
    og[H + c]     = mv;                              // -inf for empty segment
    og[2 * H + c] = (R > 0) ? (av / l_run) : 0.0f;   // l_run >= 1 when R > 0
  }
}

extern "C" void kernel_launch(void* const* d_in, const int* in_sizes, int n_in,
                              void* d_out, int out_size, void* d_ws, size_t ws_size,
                              hipStream_t stream)
{
  const float* x   = (const float*)d_in[0];
  const float* w1  = (const float*)d_in[1];
  const float* b1  = (const float*)d_in[2];
  const float* w2  = (const float*)d_in[3];
  const float* b2  = (const float*)d_in[4];
  const int*  bidx = (const int*)d_in[5];

  const int N  = in_sizes[5];            // batch_index length
  const int Bn = out_size / (3 * H);     // num graphs

  // workspace: seg_start then w1t
  char* ws = (char*)d_ws;
  size_t off = 0;
  int* seg_start = (int*)(ws + off);
  off += (size_t)(Bn + 1) * sizeof(int);
  off = (off + 255) & ~(size_t)255;
  short* w1t = (short*)(ws + off);

  prep_kernel<<<(H * H + 255) / 256, 256, 0, stream>>>(w1, w1t);
  bounds_kernel<<<(N + 255) / 256, 256, 0, stream>>>(bidx, seg_start, N, Bn);
  fused_kernel<<<Bn, 512, 0, stream>>>(x, w1t, b1, w2, b2, seg_start, (float*)d_out);
}

// Round 4
// 1218.197 us; speedup vs baseline: 1.6426x; 1.6426x over previous
//
#include <hip/hip_runtime.h>
#include <hip/hip_bf16.h>
#include <math.h>

#define H 128
#define TILE 64
#define XB_STRIDE 136   // shorts per xb row (272B) -> 2-way bank aliasing (free)
#define WB_STRIDE 9     // floats per wbuf row (36B) -> conflict-free scalar reads (9 odd)
#define MB_STRIDE 136   // merge buffer row-block stride

typedef __attribute__((ext_vector_type(8))) short bf16x8;
typedef __attribute__((ext_vector_type(4))) float f32x4;

__device__ __forceinline__ short f2bf(float f) {
  union { float f; unsigned u; } v; v.f = f;
  unsigned r = v.u + 0x7fffu + ((v.u >> 16) & 1u);  // round-to-nearest-even
  return (short)(r >> 16);
}

// ---- K0: W1 (fp32, [k][n]) -> W1T bf16 [n][k], so B-frags are contiguous 16B ----
__global__ void prep_kernel(const float* __restrict__ w1, short* __restrict__ w1t) {
  int i = blockIdx.x * blockDim.x + threadIdx.x;   // 0 .. H*H-1
  if (i >= H * H) return;
  int k = i >> 7, n = i & (H - 1);
  w1t[n * H + k] = f2bf(w1[k * H + n]);
}

// ---- K1: segment boundaries from sorted batch_index ----
__global__ void bounds_kernel(const int* __restrict__ bi, int* __restrict__ seg_start,
                              int N, int B) {
  int n = blockIdx.x * blockDim.x + threadIdx.x;
  if (n >= N) return;
  int cur = bi[n];
  int prev = (n == 0) ? -1 : bi[n - 1];
  for (int g = prev + 1; g <= cur; ++g) seg_start[g] = n;
  if (n == N - 1) {
    for (int g = cur + 1; g <= B; ++g) seg_start[g] = N;
  }
}

// ---- K2: fused per-graph readout. 8 waves x 16 cols; 2 barriers/tile;
//      all-wave duplicated softmax reduce; weights broadcast via shfl.
//      NO min-waves clamp (round-3 lesson: (512,7) -> 36 VGPR -> 5 GB spill). ----
__global__ __launch_bounds__(512) void fused_kernel(
    const float* __restrict__ x, const short* __restrict__ w1t,
    const float* __restrict__ b1, const float* __restrict__ w2,
    const float* __restrict__ b2, const int* __restrict__ seg_start,
    float* __restrict__ out)
{
  // overlay: {xb 17408B, wbuf 2304B} reused as mb[3][16][136] (26112B) after loop
  __shared__ __align__(16) char smem[3 * 16 * MB_STRIDE * 4];
  short* xb   = (short*)smem;
  float* wbuf = (float*)(smem + TILE * XB_STRIDE * 2);
  float* mb   = (float*)smem;

  const int g = blockIdx.x;
  const int s = seg_start[g];
  const int R = seg_start[g + 1] - s;

  const int tid  = threadIdx.x;
  const int w    = tid >> 6;       // wave 0..7 -> cols [16w, 16w+16)
  const int lane = tid & 63;
  const int l15  = lane & 15;
  const int q    = lane >> 4;

  // staging/pool identity: cols [c4, c4+4), rows rb + 16i (i=0..3)
  const int c4 = (tid & 31) * 4;
  const int rb = tid >> 5;         // 0..15

  float4 sum4 = make_float4(0.f, 0.f, 0.f, 0.f);
  float4 mx4  = make_float4(-INFINITY, -INFINITY, -INFINITY, -INFINITY);
  float4 av4  = make_float4(0.f, 0.f, 0.f, 0.f);
  float m_run = -INFINITY, l_run = 0.f;

  const float b2v  = b2[0];
  const int   c0   = 16 * w + l15;   // this thread's output column
  const float w2c0 = w2[c0];
  const float b1c0 = b1[c0];

  // ---- hoist loop-invariant B-fragments (column c0 of W1T), 16 VGPRs ----
  bf16x8 bfrag[4];
#pragma unroll
  for (int kk = 0; kk < 4; ++kk)
    bfrag[kk] = *(const bf16x8*)(w1t + c0 * H + 32 * kk + 8 * q);

  const float* xp = x + (size_t)s * H + c4;

  for (int t0 = 0; t0 < R; t0 += TILE) {
    const int Rt    = min(TILE, R - t0);
    const int mtMax = (Rt + 15) >> 4;          // skip all-OOB M-subtiles
    const float* xt = xp + (size_t)t0 * H;

    // ---- stage: global fp32 -> LDS bf16; fold sum/max; no register retention ----
#pragma unroll
    for (int i = 0; i < 4; ++i) {
      const int row = rb + 16 * i;
      float4 v = make_float4(0.f, 0.f, 0.f, 0.f);
      if (row < Rt) {
        v = *(const float4*)(xt + (size_t)row * H);
        sum4.x += v.x; sum4.y += v.y; sum4.z += v.z; sum4.w += v.w;
        mx4.x = fmaxf(mx4.x, v.x); mx4.y = fmaxf(mx4.y, v.y);
        mx4.z = fmaxf(mx4.z, v.z); mx4.w = fmaxf(mx4.w, v.w);
      }
      short4 sv = make_short4(f2bf(v.x), f2bf(v.y), f2bf(v.z), f2bf(v.w));
      *(short4*)(&xb[row * XB_STRIDE + c4]) = sv;   // zeros for OOB rows
    }
    __syncthreads();   // sync1: xb ready (also fences prev-tile wbuf readers)

    // ---- gate GEMM: 64 rows x 16 cols per wave, B held in registers ----
    f32x4 acc[4] = {};
#pragma unroll
    for (int kk = 0; kk < 4; ++kk) {
#pragma unroll
      for (int mt = 0; mt < 4; ++mt) {
        if (mt < mtMax) {
          const bf16x8 a = *(const bf16x8*)(&xb[(16 * mt + l15) * XB_STRIDE + 32 * kk + 8 * q]);
          acc[mt] = __builtin_amdgcn_mfma_f32_16x16x32_bf16(a, bfrag[kk], acc[mt], 0, 0, 0);
        }
      }
    }

    // ---- epilogue: silu(h)*w2, 16-lane shfl reduce -> wbuf[row][w] ----
#pragma unroll
    for (int mt = 0; mt < 4; ++mt) {
      if (mt < mtMax) {
#pragma unroll
        for (int r = 0; r < 4; ++r) {
          float h0 = acc[mt][r] + b1c0;
          float s0 = h0 / (1.0f + __expf(-h0));
          float p  = s0 * w2c0;
          p += __shfl_xor(p, 1);
          p += __shfl_xor(p, 2);
          p += __shfl_xor(p, 4);
          p += __shfl_xor(p, 8);
          if (l15 == 0) wbuf[(16 * mt + 4 * q + r) * WB_STRIDE + w] = p;
        }
      }
    }
    __syncthreads();   // sync2: wbuf ready (also fences xb readers before next stage)

    // ---- all waves duplicate: per-row gate, tile max/denom, in-register weights ----
    {
      const int row = lane;
      float gate = b2v;
#pragma unroll
      for (int j = 0; j < 8; ++j) gate += wbuf[row * WB_STRIDE + j];
      const bool valid = row < Rt;
      float gm = valid ? gate : -INFINITY;
#pragma unroll
      for (int m2 = 1; m2 < 64; m2 <<= 1) gm = fmaxf(gm, __shfl_xor(gm, m2));
      const float m_new = fmaxf(m_run, gm);
      const float wv = valid ? __expf(gate - m_new) : 0.f;
      float tl = wv;
#pragma unroll
      for (int m2 = 1; m2 < 64; m2 <<= 1) tl += __shfl_xor(tl, m2);
      const float corr = __expf(m_run - m_new);   // first tile: exp(-inf)=0
      m_run = m_new;
      l_run = l_run * corr + tl;
      av4.x *= corr; av4.y *= corr; av4.z *= corr; av4.w *= corr;

      // ---- pool: re-read x (L2-hot), weights via in-wave shfl, 1 fma/elem ----
#pragma unroll
      for (int i = 0; i < 4; ++i) {
        const int row2 = rb + 16 * i;
        const float wvi = __shfl(wv, row2);      // wv==0 for rows >= Rt
        if (row2 < Rt) {
          const float4 v = *(const float4*)(xt + (size_t)row2 * H);
          av4.x += wvi * v.x; av4.y += wvi * v.y;
          av4.z += wvi * v.z; av4.w += wvi * v.w;
        }
      }
    }
    // no barrier: next xb write is after this thread's pool pass (program order),
    // and sync2 already guaranteed all waves' GEMM reads of xb are complete.
    // next wbuf write is after sync1(t+1), which requires all waves done here.
  }

  __syncthreads();   // all waves done with xb/wbuf before overlaying mb

  // ---- merge the 16 row-block partials per column (mb overlays smem) ----
  {
    const int base = rb * MB_STRIDE + c4;
    *(float4*)(&mb[       base]) = sum4;
    *(float4*)(&mb[2176 + base]) = mx4;
    *(float4*)(&mb[4352 + base]) = av4;
  }
  __syncthreads();
  if (tid < H) {
    const int c = tid;
    float sv = 0.f, mv = -INFINITY, av = 0.f;
#pragma unroll
    for (int r16 = 0; r16 < 16; ++r16) {
      sv += mb[r16 * MB_STRIDE + c];
      mv  = fmaxf(mv, mb[2176 + r16 * MB_STRIDE + c]);
      av += mb[4352 + r16 * MB_STRIDE + c];
    }
    float* og = out + (size_t)g * (3 * H);
    og[c]         = sv / fmaxf((float)R, 1.0f);
    og[H + c]     = mv;                              // -inf for empty segment
    og[2 * H + c] = (R > 0) ? (av / l_run) : 0.0f;   // l_run >= 1 when R > 0
  }
}

extern "C" void kernel_launch(void* const* d_in, const int* in_sizes, int n_in,
                              void* d_out, int out_size, void* d_ws, size_t ws_size,
                              hipStream_t stream)
{
  const float* x   = (const float*)d_in[0];
  const float* w1  = (const float*)d_in[1];
  const float* b1  = (const float*)d_in[2];
  const float* w2  = (const float*)d_in[3];
  const float* b2  = (const float*)d_in[4];
  const int*  bidx = (const int*)d_in[5];

  const int N  = in_sizes[5];            // batch_index length
  const int Bn = out_size / (3 * H);     // num graphs

  // workspace: seg_start then w1t
  char* ws = (char*)d_ws;
  size_t off = 0;
  int* seg_start = (int*)(ws + off);
  off += (size_t)(Bn + 1) * sizeof(int);
  off = (off + 255) & ~(size_t)255;
  short* w1t = (short*)(ws + off);

  prep_kernel<<<(H * H + 255) / 256, 256, 0, stream>>>(w1, w1t);
  bounds_kernel<<<(N + 255) / 256, 256, 0, stream>>>(bidx, seg_start, N, Bn);
  fused_kernel<<<Bn, 512, 0, stream>>>(x, w1t, b1, w2, b2, seg_start, (float*)d_out);
}